// Round 3
// baseline (559.551 us; speedup 1.0000x reference)
//
#include <hip/hip_runtime.h>
#include <cstdint>

// Problem constants (fixed instance: B=8192, Cin=4096, Cout=1024, T=10)
#define B_DIM 8192
#define CIN   4096
#define COUT  1024

// Fixed-point quantization of W: 23-bit minus headroom so top balanced digit <= 127.
constexpr double W_SCALE   = 83230720.0;        // (2^23 - 2^16) / 0.1
constexpr int    QMAX      = 8323072;           // 2^23 - 2^16
constexpr double INV_SCALE = 0.1 / 8323072.0;   // 1 / W_SCALE

using i32x4 = __attribute__((ext_vector_type(4))) int;

// ---- async global->LDS, 16B per lane. LDS dest is wave-uniform base + lane*16.
__device__ __forceinline__ void async_copy16(void* lds, const void* g) {
    auto l = (__attribute__((address_space(3))) void*)(uintptr_t)(lds);
    auto p = (const __attribute__((address_space(1))) void*)(uintptr_t)(g);
    __builtin_amdgcn_global_load_lds(p, l, 16, 0, 0);
}

// ---------------------------------------------------------------------------
// Kernel 1: x (fp32 0/1) -> i8. 16 elements per thread.
__global__ void prep_x(const float* __restrict__ x, int8_t* __restrict__ Ai) {
    const int idx = blockIdx.x * 256 + threadIdx.x;      // 2,097,152 threads
    const float4* xp = (const float4*)x + (size_t)idx * 4;
    float4 v0 = xp[0], v1 = xp[1], v2 = xp[2], v3 = xp[3];
    auto pk = [](float a, float b, float c, float d) -> int {
        return (a != 0.f ? 1 : 0) | ((b != 0.f ? 1 : 0) << 8) |
               ((c != 0.f ? 1 : 0) << 16) | ((d != 0.f ? 1 : 0) << 24);
    };
    int4 r;
    r.x = pk(v0.x, v0.y, v0.z, v0.w);
    r.y = pk(v1.x, v1.y, v1.z, v1.w);
    r.z = pk(v2.x, v2.y, v2.z, v2.w);
    r.w = pk(v3.x, v3.y, v3.z, v3.w);
    ((int4*)Ai)[idx] = r;
}

// ---------------------------------------------------------------------------
// Kernel 2: W (fp32) -> 3 balanced base-256 digit planes (i8), stacked N-major.
__global__ void prep_w(const float* __restrict__ W, int8_t* __restrict__ Bd,
                       unsigned long long* __restrict__ cm) {
    const int idx = blockIdx.x * 256 + threadIdx.x;      // 1,048,576 threads, 4 elems each
    float4 w = ((const float4*)W)[idx];
    float ws[4] = {w.x, w.y, w.z, w.w};
    char dg[3][4];
#pragma unroll
    for (int k = 0; k < 4; ++k) {
        int qv = __double2int_rn((double)ws[k] * W_SCALE);
        qv = max(0, min(QMAX, qv));
        int d0 = ((qv + 128) & 255) - 128; int tq = (qv - d0) >> 8;
        int d1 = ((tq + 128) & 255) - 128; int d2 = (tq - d1) >> 8;   // d2 in [0,127]
        dg[0][k] = (char)d0; dg[1][k] = (char)d1; dg[2][k] = (char)d2;
    }
    const size_t off = (size_t)idx * 4;  // = j*4096 + c (no row crossing: 4096 % 4 == 0)
#pragma unroll
    for (int p = 0; p < 3; ++p) {
        char4 c4; c4.x = dg[p][0]; c4.y = dg[p][1]; c4.z = dg[p][2]; c4.w = dg[p][3];
        *(char4*)(Bd + (size_t)p * COUT * CIN + off) = c4;
    }
    if (idx < COUT) cm[idx] = 0ull;
}

// ---------------------------------------------------------------------------
// Kernel 3: plane-fused i8 GEMM + fp64 combine + in-block column max.
//   Tile: 128 rows x 256 combined output cols; 3 digit planes per block.
//   Grid 256 = one balanced dispatch round (1 block/CU). 8 waves (2M x 4N).
//   NEW vs round 2: register-level read-prefetch. Step s issues the ds_reads
//   for step s+1 into an alternate reg set (aK0/aK1, bA/bB ping-pong), waits
//   lgkmcnt(just-issued) + sched_barrier(0), then runs step-s MFMAs -> reads
//   fly UNDER the MFMA cluster (round-2 counters showed reads+MFMA fully
//   serialized: 7870 cy/tile = 3917 MFMA + 3970 LDS). Barriers cut 12 -> 6
//   per K-tile (one per step). Fence ledger (per tile t, steps S0..S5):
//     stages:  SB2(t)@S0, SA(t+1)@S1, SB0(t+1)@S4, SB1(t+1)@S5
//     read-fence (stage >= last-read-issue + 2 w/ W-before-BAR): all hold
//     land-confirm: VMW(0) end-S0 {SB2}, end-S4 {SA,SB0}, end-S5 {SB1};
//       each drain's queue holds ONLY loads needed next step, issued one full
//       MFMA cluster (~650 cy) earlier -> L2-hit latency (200-400 cy) covered.
//   LDS: A 2x16K dbuf | B plane p at 32768 + p*32768 (single-buffered).
//   Epilogue: exact i64 combine -> fp64 Sc + in-block column max -> cm.
__device__ __forceinline__ void mma16(const i32x4 (&a)[4], const i32x4 (&b)[4],
                                      i32x4 (*accp)[4]) {
    __builtin_amdgcn_s_setprio(1);
#pragma unroll
    for (int mi = 0; mi < 4; ++mi)
#pragma unroll
        for (int ni = 0; ni < 4; ++ni)
            accp[mi][ni] = __builtin_amdgcn_mfma_i32_16x16x64_i8(
                a[mi], b[ni], accp[mi][ni], 0, 0, 0);
    __builtin_amdgcn_s_setprio(0);
}

#define BAR()    __builtin_amdgcn_s_barrier()
#define SCHED0() __builtin_amdgcn_sched_barrier(0)
#define W0()     asm volatile("s_waitcnt lgkmcnt(0)" ::: "memory")
#define W4()     asm volatile("s_waitcnt lgkmcnt(4)" ::: "memory")
#define W8()     asm volatile("s_waitcnt lgkmcnt(8)" ::: "memory")
#define VMW0()   asm volatile("s_waitcnt vmcnt(0)" ::: "memory")

__global__ __launch_bounds__(512, 2) void gemm_i8(const int8_t* __restrict__ A,
                                                  const int8_t* __restrict__ Bm,
                                                  double* __restrict__ Sc,
                                                  unsigned long long* __restrict__ cm) {
    __shared__ alignas(16) int8_t lds[131072];
    const int tid  = threadIdx.x;
    const int lane = tid & 63;
    const int wave = tid >> 6;

    // XCD mapping: round-robin dispatch -> XCD = wg&7, so bn = wg&3 is
    // XCD-stable (each XCD's 3 MB B-slice stays L2-resident).
    const int wg = (int)blockIdx.x;
    const int bn = wg & 3;           // 0..3   (256 combined columns each)
    const int bm = wg >> 2;          // 0..63  (128 rows each)

    // staging: thread t owns LDS slot (row tid>>3, chunk tid&7), fetches
    // pre-swizzled global chunk (tid&7) ^ (row&7).
    const int stid   = tid >> 3;                            // 0..63
    const int cswz16 = ((tid & 7) ^ (stid & 7)) << 4;
    const int8_t* gA = A  + (size_t)(bm * 128 + stid) * CIN + cswz16;
    const int8_t* gB = Bm + (size_t)(bn * 256 + stid) * CIN + cswz16;
    const int wv1024 = wave << 10;

#define SA_(t_) do {                                                            \
    int8_t* d_ = lds + (((t_) & 1) << 14) + wv1024;                             \
    const int8_t* s_ = gA + ((t_) << 7);                                        \
    async_copy16(d_,        s_);                                                \
    async_copy16(d_ + 8192, s_ + (size_t)64 * CIN);                             \
} while (0)
#define SB_(t_, p_) do {                                                        \
    int8_t* d_ = lds + 32768 + ((p_) << 15) + wv1024;                           \
    const int8_t* s_ = gB + (size_t)(p_) * COUT * CIN + ((t_) << 7);            \
    async_copy16(d_,         s_);                                               \
    async_copy16(d_ + 8192,  s_ + (size_t)64  * CIN);                           \
    async_copy16(d_ + 16384, s_ + (size_t)128 * CIN);                           \
    async_copy16(d_ + 24576, s_ + (size_t)192 * CIN);                           \
} while (0)

    // fragment addressing (16x16x64: lane holds [m=lane&15][16B at k-chunk q])
    const int wr = wave >> 2, wc = wave & 3;
    const int fr = lane & 15;
    const int q  = lane >> 4;
    const int ck0 = (q ^ (fr & 7)) << 4;        // swizzled chunk, kk0; kk1 = ^64
    const int abase = (wr * 64 + fr) * 128;     // + mi*2048 + Abuf*16384
    const int bbase = (wc * 64 + fr) * 128;     // + ni*2048 + 32768 + p*32768

    i32x4 aK0[4], aK1[4], bA[4], bB[4];
    i32x4 acc[3][4][4] = {};

#define LDA_(dst_, t_, kk_) do {                                                \
    const int8_t* p_ = lds + (((t_) & 1) << 14) + abase + (ck0 ^ ((kk_) * 64)); \
    dst_[0] = *(const i32x4*)(p_);        dst_[1] = *(const i32x4*)(p_ + 2048); \
    dst_[2] = *(const i32x4*)(p_ + 4096); dst_[3] = *(const i32x4*)(p_ + 6144); \
} while (0)
#define LDB_(dst_, p_, kk_) do {                                                \
    const int8_t* q_ = lds + 32768 + ((p_) << 15) + bbase + (ck0 ^ ((kk_) * 64)); \
    dst_[0] = *(const i32x4*)(q_);        dst_[1] = *(const i32x4*)(q_ + 2048); \
    dst_[2] = *(const i32x4*)(q_ + 4096); dst_[3] = *(const i32x4*)(q_ + 6144); \
} while (0)

    // ---- prologue: stage A(0), B0(0), B1(0); drain; preload S0 operands ----
    SA_(0); SB_(0, 0); SB_(0, 1);
    VMW0(); BAR();
    LDB_(bB, 0, 0); LDA_(aK0, 0, 0);     // 8 reads, awaited by S0's W4

#pragma unroll 1
    for (int t = 0; t < 31; ++t) {
        // S0: mma p0/kk0 on (aK0,bB); prefetch b1_kk0; stage B2(t)
        LDB_(bA, 1, 0); SB_(t, 2);
        W4(); SCHED0(); mma16(aK0, bB, acc[0]); VMW0(); BAR();
        // S1: mma p1/kk0 on (aK0,bA); prefetch b2_kk0; stage A(t+1)
        LDB_(bB, 2, 0); SA_(t + 1);
        W4(); SCHED0(); mma16(aK0, bA, acc[1]); BAR();
        // S2: mma p2/kk0 on (aK0,bB); prefetch b0_kk1 + a_kk1
        LDB_(bA, 0, 1); LDA_(aK1, t, 1);
        W8(); SCHED0(); mma16(aK0, bB, acc[2]); BAR();
        // S3: mma p0/kk1 on (aK1,bA); prefetch b1_kk1
        LDB_(bB, 1, 1);
        W4(); SCHED0(); mma16(aK1, bA, acc[0]); BAR();
        // S4: mma p1/kk1 on (aK1,bB); prefetch b2_kk1; stage B0(t+1)
        LDB_(bA, 2, 1); SB_(t + 1, 0);
        W4(); SCHED0(); mma16(aK1, bB, acc[1]); VMW0(); BAR();
        // S5: mma p2/kk1 on (aK1,bA); prefetch next-tile b0_kk0 + a_kk0; stage B1(t+1)
        LDB_(bB, 0, 0); LDA_(aK0, t + 1, 0); SB_(t + 1, 1);
        W8(); SCHED0(); mma16(aK1, bA, acc[2]); VMW0(); BAR();
    }
    // ---- tail: t = 31 (no next-tile stages; B2(31) still staged at S0) ----
    LDB_(bA, 1, 0); SB_(31, 2);
    W4(); SCHED0(); mma16(aK0, bB, acc[0]); VMW0(); BAR();
    LDB_(bB, 2, 0);
    W4(); SCHED0(); mma16(aK0, bA, acc[1]); BAR();
    LDB_(bA, 0, 1); LDA_(aK1, 31, 1);
    W8(); SCHED0(); mma16(aK0, bB, acc[2]); BAR();
    LDB_(bB, 1, 1);
    W4(); SCHED0(); mma16(aK1, bA, acc[0]); BAR();
    LDB_(bA, 2, 1);
    W4(); SCHED0(); mma16(aK1, bB, acc[1]); BAR();
    W0(); SCHED0(); mma16(aK1, bA, acc[2]);
    BAR();

    // ---- epilogue: exact fp64 combine + store + in-block column max ----
    // C/D layout: col = lane&15 (N, from b), row = (lane>>4)*4 + reg (M, from a)
    const int gm0 = bm * 128 + wr * 64 + q * 4;
    const int gn0 = bn * 256 + wc * 64 + fr;
    double vmax[4] = {0.0, 0.0, 0.0, 0.0};
#pragma unroll
    for (int mi = 0; mi < 4; ++mi)
#pragma unroll
        for (int ni = 0; ni < 4; ++ni) {
            const int gn = gn0 + ni * 16;
#pragma unroll
            for (int reg = 0; reg < 4; ++reg) {
                const int gm = gm0 + mi * 16 + reg;
                long long isum = (long long)acc[0][mi][ni][reg]
                               + 256ll   * (long long)acc[1][mi][ni][reg]
                               + 65536ll * (long long)acc[2][mi][ni][reg];
                double v = (double)isum * INV_SCALE;   // bit-identical to old path
                Sc[(size_t)gm * COUT + gn] = v;
                vmax[ni] = fmax(vmax[ni], v);
            }
        }
#pragma unroll
    for (int ni = 0; ni < 4; ++ni) {
        vmax[ni] = fmax(vmax[ni], __shfl_xor(vmax[ni], 16, 64));
        vmax[ni] = fmax(vmax[ni], __shfl_xor(vmax[ni], 32, 64));
    }
    double* red = (double*)lds;      // reuses Abuf[0]; all LDS reads long done
    if (lane < 16) {
#pragma unroll
        for (int ni = 0; ni < 4; ++ni)
            red[wave * 64 + ni * 16 + fr] = vmax[ni];
    }
    __syncthreads();
    if (tid < 256) {
        const int c = tid;                       // column within block: wc*64+ni*16+fr
        const int wcq = c >> 6, nic = (c >> 4) & 3, frc = c & 15;
        double m = fmax(red[wcq * 64 + nic * 16 + frc],
                        red[(wcq + 4) * 64 + nic * 16 + frc]);
        atomicMax(cm + bn * 256 + c, (unsigned long long)__double_as_longlong(m));
    }
#undef SA_
#undef SB_
#undef LDA_
#undef LDB_
}

// ---------------------------------------------------------------------------
// Kernel 4: LIF/WTA scan, one wave per batch row, 16 fp64 neurons per lane.
__global__ void scan_k(const double* __restrict__ Sc, const unsigned long long* __restrict__ cm,
                       const int* __restrict__ twp, float* __restrict__ out) {
    const int lane = threadIdx.x & 63;
    const int wave = threadIdx.x >> 6;
    const int b = blockIdx.x * 4 + wave;
    const int T = *twp;
    const double* row = Sc + (size_t)b * COUT;

    double iv[16], mem[16], thr[16];
    int cnt[16];
    double imax = 0.0;
#pragma unroll
    for (int u = 0; u < 16; ++u) {
        const int j = lane + u * 64;
        iv[u]  = row[j];
        thr[u] = 3.0 * __longlong_as_double((long long)cm[j]);
        mem[u] = 0.0; cnt[u] = 0;
        imax = fmax(imax, iv[u]);
    }
#pragma unroll
    for (int d = 32; d >= 1; d >>= 1) imax = fmax(imax, __shfl_xor(imax, d, 64));
    const double h = 1.625 * imax;   // INH * imax

    for (int t = 0; t < T; ++t) {
        int first = 0x7fffffff;
        bool sp[16];
#pragma unroll
        for (int u = 0; u < 16; ++u) {
            mem[u] = mem[u] * 0.99 + iv[u];
            sp[u] = mem[u] > thr[u];
            if (sp[u]) first = min(first, lane + u * 64);
        }
#pragma unroll
        for (int d = 32; d >= 1; d >>= 1) first = min(first, __shfl_xor(first, d, 64));
        const bool rowspike = first < 0x7fffffff;
#pragma unroll
        for (int u = 0; u < 16; ++u) {
            if (sp[u]) mem[u] = 0.0;
            if (rowspike) {
                if (lane + u * 64 == first) cnt[u]++;
                else mem[u] -= h;
            }
        }
    }
#pragma unroll
    for (int u = 0; u < 16; ++u)
        out[(size_t)b * COUT + lane + u * 64] = (float)cnt[u];
}

// ---------------------------------------------------------------------------
extern "C" void kernel_launch(void* const* d_in, const int* in_sizes, int n_in,
                              void* d_out, int out_size, void* d_ws, size_t ws_size,
                              hipStream_t stream) {
    const float* x  = (const float*)d_in[0];
    const float* W  = (const float*)d_in[1];
    const int*   tw = (const int*)d_in[2];
    float* out = (float*)d_out;

    int8_t* Ai = (int8_t*)d_ws;                                   // 33,554,432 B
    int8_t* Bd = Ai + (size_t)B_DIM * CIN;                        // 12,582,912 B
    double* Sc = (double*)(Bd + (size_t)3 * COUT * CIN);          // 67,108,864 B
    unsigned long long* cm =
        (unsigned long long*)((int8_t*)Sc + (size_t)B_DIM * COUT * 8);  // 8,192 B

    hipLaunchKernelGGL(prep_x,  dim3(8192), dim3(256), 0, stream, x, Ai);
    hipLaunchKernelGGL(prep_w,  dim3(4096), dim3(256), 0, stream, W, Bd, cm);
    hipLaunchKernelGGL(gemm_i8, dim3(256),  dim3(512), 0, stream, Ai, Bd, Sc, cm);
    hipLaunchKernelGGL(scan_k,  dim3(2048), dim3(256), 0, stream, Sc, cm, tw, out);
}

// Round 4
// 321.965 us; speedup vs baseline: 1.7379x; 1.7379x over previous
//
#include <hip/hip_runtime.h>
#include <cstdint>

// Problem constants (fixed instance: B=8192, Cin=4096, Cout=1024, T=10)
#define B_DIM 8192
#define CIN   4096
#define COUT  1024

// Fixed-point quantization of W: 23-bit minus headroom so top balanced digit <= 127.
constexpr double W_SCALE   = 83230720.0;        // (2^23 - 2^16) / 0.1
constexpr int    QMAX      = 8323072;           // 2^23 - 2^16
constexpr double INV_SCALE = 0.1 / 8323072.0;   // 1 / W_SCALE

using i32x4 = __attribute__((ext_vector_type(4))) int;

// ---- async global->LDS, 16B per lane. LDS dest is wave-uniform base + lane*16.
__device__ __forceinline__ void async_copy16(void* lds, const void* g) {
    auto l = (__attribute__((address_space(3))) void*)(uintptr_t)(lds);
    auto p = (const __attribute__((address_space(1))) void*)(uintptr_t)(g);
    __builtin_amdgcn_global_load_lds(p, l, 16, 0, 0);
}

// ---------------------------------------------------------------------------
// Kernel 1: x (fp32 0/1) -> i8. 16 elements per thread.
__global__ void prep_x(const float* __restrict__ x, int8_t* __restrict__ Ai) {
    const int idx = blockIdx.x * 256 + threadIdx.x;      // 2,097,152 threads
    const float4* xp = (const float4*)x + (size_t)idx * 4;
    float4 v0 = xp[0], v1 = xp[1], v2 = xp[2], v3 = xp[3];
    auto pk = [](float a, float b, float c, float d) -> int {
        return (a != 0.f ? 1 : 0) | ((b != 0.f ? 1 : 0) << 8) |
               ((c != 0.f ? 1 : 0) << 16) | ((d != 0.f ? 1 : 0) << 24);
    };
    int4 r;
    r.x = pk(v0.x, v0.y, v0.z, v0.w);
    r.y = pk(v1.x, v1.y, v1.z, v1.w);
    r.z = pk(v2.x, v2.y, v2.z, v2.w);
    r.w = pk(v3.x, v3.y, v3.z, v3.w);
    ((int4*)Ai)[idx] = r;
}

// ---------------------------------------------------------------------------
// Kernel 2: W (fp32) -> 3 balanced base-256 digit planes (i8), stacked N-major.
__global__ void prep_w(const float* __restrict__ W, int8_t* __restrict__ Bd,
                       unsigned long long* __restrict__ cm) {
    const int idx = blockIdx.x * 256 + threadIdx.x;      // 1,048,576 threads, 4 elems each
    float4 w = ((const float4*)W)[idx];
    float ws[4] = {w.x, w.y, w.z, w.w};
    char dg[3][4];
#pragma unroll
    for (int k = 0; k < 4; ++k) {
        int qv = __double2int_rn((double)ws[k] * W_SCALE);
        qv = max(0, min(QMAX, qv));
        int d0 = ((qv + 128) & 255) - 128; int tq = (qv - d0) >> 8;
        int d1 = ((tq + 128) & 255) - 128; int d2 = (tq - d1) >> 8;   // d2 in [0,127]
        dg[0][k] = (char)d0; dg[1][k] = (char)d1; dg[2][k] = (char)d2;
    }
    const size_t off = (size_t)idx * 4;  // = j*4096 + c (no row crossing: 4096 % 4 == 0)
#pragma unroll
    for (int p = 0; p < 3; ++p) {
        char4 c4; c4.x = dg[p][0]; c4.y = dg[p][1]; c4.z = dg[p][2]; c4.w = dg[p][3];
        *(char4*)(Bd + (size_t)p * COUT * CIN + off) = c4;
    }
    if (idx < COUT) cm[idx] = 0ull;
}

// ---------------------------------------------------------------------------
// Kernel 3: plane-fused i8 GEMM + fp64 combine + in-block column max.
//   ROUND-4 RESTRUCTURE (round 3 spilled: +370 MB scratch writes from 64
//   extra operand regs on top of acc=192). Overlap now comes from 2 blocks/CU
//   TLP (m114: MFMA and LDS pipes of independent blocks co-schedule), which
//   costs ZERO registers:
//     - 256-thread blocks (4 waves, 2M x 2N), tile 128 rows x 64 combined
//       cols, BK=128. Per wave 64x32 per plane -> acc = 3*4*2 = 96 regs,
//       a[8]+b[4] = 48 operand regs, ~180 total (<=256 -> 8 waves/CU -> 2
//       blocks/CU; LDS 40960 B/block, 2x40K <= 160K).
//     - Grid 1024 = 2 balanced dispatch rounds of 512 co-resident blocks.
//     - 3 phases/tile (one per plane, 16 MFMA each), ONE barrier per phase.
//       Fence proof: every ds_read is consumed by an MFMA (compiler lgkm
//       wait) before the phase BAR, so any stage issued after that BAR
//       cannot overwrite data still being read. Stage ledger (per tile t):
//         P0: stage B2(t);   P1: stage A(t+1), B0(t+1);   P2: stage B1(t+1)
//       VMW ledger (per-thread 16B loads, FIFO; SA=4, SB=2):
//         entry: [B1(t)]=2
//         P0: +B2(t) -> [B1 2|B2 2];        VMW(2) drains B1
//         P1: +A,B0  -> [B2 2|A 4|B0 2];    VMW(6) drains B2
//         P2: +B1    -> [A 4|B0 2|B1 2];    VMW(2) drains A,B0 -> entry state
//       Never vmcnt(0) in the loop; each load checked >=1 full phase after
//       issue. XCD map: bn = (wg&7)*2 | ((wg>>3)&1) -> each XCD holds a
//       1.5 MB B-slice L2-resident; A streams via LLC.
//   Epilogue: exact i64 combine -> fp64 Sc + in-block column max -> cm.
__device__ __forceinline__ void mma16(const i32x4 (&a)[8], const i32x4 (&b)[4],
                                      i32x4 (*accp)[2]) {
    __builtin_amdgcn_s_setprio(1);
#pragma unroll
    for (int kk = 0; kk < 2; ++kk)
#pragma unroll
        for (int mi = 0; mi < 4; ++mi)
#pragma unroll
            for (int ni = 0; ni < 2; ++ni)
                accp[mi][ni] = __builtin_amdgcn_mfma_i32_16x16x64_i8(
                    a[kk * 4 + mi], b[kk * 2 + ni], accp[mi][ni], 0, 0, 0);
    __builtin_amdgcn_s_setprio(0);
}

#define BAR()    __builtin_amdgcn_s_barrier()
#define SCHED0() __builtin_amdgcn_sched_barrier(0)
#define VMW(n)   asm volatile("s_waitcnt vmcnt(" #n ")" ::: "memory")

__global__ __launch_bounds__(256, 2) void gemm_i8(const int8_t* __restrict__ A,
                                                  const int8_t* __restrict__ Bm,
                                                  double* __restrict__ Sc,
                                                  unsigned long long* __restrict__ cm) {
    // [0,16384) = A (128 rows x 128B); plane p at 16384 + p*8192 (64 x 128B)
    __shared__ alignas(16) int8_t lds[40960];
    const int tid  = threadIdx.x;
    const int lane = tid & 63;
    const int wave = tid >> 6;

    // XCD-aware mapping (1024 wgs, round-robin wg -> XCD wg&7):
    const int wg = (int)blockIdx.x;
    const int bn = ((wg & 7) << 1) | ((wg >> 3) & 1);   // 0..15 (64 cols each)
    const int bm = wg >> 4;                             // 0..63 (128 rows each)

    // staging: thread t owns LDS slot (row tid>>3 (+32/call), chunk tid&7),
    // fetches pre-swizzled global chunk (tid&7) ^ (row&7). (row&7)==(stid&7)
    // for every call since call strides are multiples of 8 rows.
    const int stid   = tid >> 3;                            // 0..31
    const int cswz16 = ((tid & 7) ^ (stid & 7)) << 4;
    const int8_t* gA = A  + (size_t)(bm * 128 + stid) * CIN + cswz16;
    const int8_t* gB = Bm + (size_t)(bn * 64  + stid) * CIN + cswz16;
    const int wv1024 = wave << 10;

#define SA_(t_) do {                                                            \
    int8_t* d_ = lds + wv1024;                                                  \
    const int8_t* s_ = gA + ((t_) << 7);                                        \
    async_copy16(d_,         s_);                                               \
    async_copy16(d_ + 4096,  s_ + (size_t)32 * CIN);                            \
    async_copy16(d_ + 8192,  s_ + (size_t)64 * CIN);                            \
    async_copy16(d_ + 12288, s_ + (size_t)96 * CIN);                            \
} while (0)
#define SB_(t_, p_) do {                                                        \
    int8_t* d_ = lds + 16384 + ((p_) << 13) + wv1024;                           \
    const int8_t* s_ = gB + (size_t)(p_) * COUT * CIN + ((t_) << 7);            \
    async_copy16(d_,        s_);                                                \
    async_copy16(d_ + 4096, s_ + (size_t)32 * CIN);                             \
} while (0)

    // fragment addressing (16x16x64: lane holds [m=lane&15][16B at k-chunk q])
    const int wr = wave >> 1, wc = wave & 1;
    const int fr = lane & 15;
    const int q  = lane >> 4;
    const int ck0 = (q ^ (fr & 7)) << 4;        // swizzled chunk, kk0; kk1 = ^64
    const int abase = (wr * 64 + fr) * 128;     // + mi*2048, kk via ck0^64
    const int bbase = 16384 + (wc * 32 + fr) * 128;   // + p*8192 + ni*2048

    i32x4 a[8], b[4];
    i32x4 acc[3][4][2] = {};

#define LDA_() do {                                                             \
    const int8_t* p_ = lds + abase;                                             \
    _Pragma("unroll")                                                           \
    for (int kk_ = 0; kk_ < 2; ++kk_)                                           \
        _Pragma("unroll")                                                       \
        for (int mi_ = 0; mi_ < 4; ++mi_)                                       \
            a[kk_ * 4 + mi_] = *(const i32x4*)(p_ + mi_ * 2048 + (ck0 ^ (kk_ * 64))); \
} while (0)
#define LDB_(p_) do {                                                           \
    const int8_t* q_ = lds + ((p_) << 13) + bbase;                              \
    _Pragma("unroll")                                                           \
    for (int kk_ = 0; kk_ < 2; ++kk_)                                           \
        _Pragma("unroll")                                                       \
        for (int ni_ = 0; ni_ < 2; ++ni_)                                       \
            b[kk_ * 2 + ni_] = *(const i32x4*)(q_ + ni_ * 2048 + (ck0 ^ (kk_ * 64))); \
} while (0)

    // ---- prologue: stage A(0), B0(0), B1(0); queue [A4|B0 2|B1 2] ----
    SA_(0); SB_(0, 0); SB_(0, 1);
    VMW(2); BAR(); SCHED0();      // A(0), B0(0) landed; B1(0) still in flight

#pragma unroll 1
    for (int t = 0; t < 31; ++t) {
        // P0 (plane 0): reads a8 + b0; stage B2(t)
        LDA_(); LDB_(0); SB_(t, 2);
        mma16(a, b, acc[0]); VMW(2); BAR(); SCHED0();
        // P1 (plane 1): reads b1; stage A(t+1) + B0(t+1)
        LDB_(1); SA_(t + 1); SB_(t + 1, 0);
        mma16(a, b, acc[1]); VMW(6); BAR(); SCHED0();
        // P2 (plane 2): reads b2; stage B1(t+1)
        LDB_(2); SB_(t + 1, 1);
        mma16(a, b, acc[2]); VMW(2); BAR(); SCHED0();
    }
    // ---- tail: t = 31 (no next-tile stages; waits relax) ----
    LDA_(); LDB_(0); SB_(31, 2);
    mma16(a, b, acc[0]); VMW(2); BAR(); SCHED0();
    LDB_(1);
    mma16(a, b, acc[1]); VMW(0); BAR(); SCHED0();
    LDB_(2);
    mma16(a, b, acc[2]); BAR();

    // ---- epilogue: exact fp64 combine + store + in-block column max ----
    // C/D layout: col = lane&15 (N, from b), row = (lane>>4)*4 + reg (M, from a)
    const int gm0 = bm * 128 + wr * 64 + q * 4;
    const int gn0 = bn * 64 + wc * 32 + fr;
    double vmax[2] = {0.0, 0.0};
#pragma unroll
    for (int mi = 0; mi < 4; ++mi)
#pragma unroll
        for (int ni = 0; ni < 2; ++ni) {
            const int gn = gn0 + ni * 16;
#pragma unroll
            for (int reg = 0; reg < 4; ++reg) {
                const int gm = gm0 + mi * 16 + reg;
                long long isum = (long long)acc[0][mi][ni][reg]
                               + 256ll   * (long long)acc[1][mi][ni][reg]
                               + 65536ll * (long long)acc[2][mi][ni][reg];
                double v = (double)isum * INV_SCALE;   // bit-identical to old path
                Sc[(size_t)gm * COUT + gn] = v;
                vmax[ni] = fmax(vmax[ni], v);
            }
        }
#pragma unroll
    for (int ni = 0; ni < 2; ++ni) {
        vmax[ni] = fmax(vmax[ni], __shfl_xor(vmax[ni], 16, 64));
        vmax[ni] = fmax(vmax[ni], __shfl_xor(vmax[ni], 32, 64));
    }
    double* red = (double*)lds;      // reuse A region; all LDS reads done (BAR)
    if (lane < 16) {
#pragma unroll
        for (int ni = 0; ni < 2; ++ni)
            red[wave * 32 + ni * 16 + fr] = vmax[ni];   // idx = wr*64 + col
    }
    __syncthreads();
    if (tid < 64) {
        const int c = tid;                              // col within block
        double m = fmax(red[c], red[64 + c]);
        atomicMax(cm + bn * 64 + c, (unsigned long long)__double_as_longlong(m));
    }
#undef SA_
#undef SB_
#undef LDA_
#undef LDB_
}

// ---------------------------------------------------------------------------
// Kernel 4: LIF/WTA scan, one wave per batch row, 16 fp64 neurons per lane.
__global__ void scan_k(const double* __restrict__ Sc, const unsigned long long* __restrict__ cm,
                       const int* __restrict__ twp, float* __restrict__ out) {
    const int lane = threadIdx.x & 63;
    const int wave = threadIdx.x >> 6;
    const int b = blockIdx.x * 4 + wave;
    const int T = *twp;
    const double* row = Sc + (size_t)b * COUT;

    double iv[16], mem[16], thr[16];
    int cnt[16];
    double imax = 0.0;
#pragma unroll
    for (int u = 0; u < 16; ++u) {
        const int j = lane + u * 64;
        iv[u]  = row[j];
        thr[u] = 3.0 * __longlong_as_double((long long)cm[j]);
        mem[u] = 0.0; cnt[u] = 0;
        imax = fmax(imax, iv[u]);
    }
#pragma unroll
    for (int d = 32; d >= 1; d >>= 1) imax = fmax(imax, __shfl_xor(imax, d, 64));
    const double h = 1.625 * imax;   // INH * imax

    for (int t = 0; t < T; ++t) {
        int first = 0x7fffffff;
        bool sp[16];
#pragma unroll
        for (int u = 0; u < 16; ++u) {
            mem[u] = mem[u] * 0.99 + iv[u];
            sp[u] = mem[u] > thr[u];
            if (sp[u]) first = min(first, lane + u * 64);
        }
#pragma unroll
        for (int d = 32; d >= 1; d >>= 1) first = min(first, __shfl_xor(first, d, 64));
        const bool rowspike = first < 0x7fffffff;
#pragma unroll
        for (int u = 0; u < 16; ++u) {
            if (sp[u]) mem[u] = 0.0;
            if (rowspike) {
                if (lane + u * 64 == first) cnt[u]++;
                else mem[u] -= h;
            }
        }
    }
#pragma unroll
    for (int u = 0; u < 16; ++u)
        out[(size_t)b * COUT + lane + u * 64] = (float)cnt[u];
}

// ---------------------------------------------------------------------------
extern "C" void kernel_launch(void* const* d_in, const int* in_sizes, int n_in,
                              void* d_out, int out_size, void* d_ws, size_t ws_size,
                              hipStream_t stream) {
    const float* x  = (const float*)d_in[0];
    const float* W  = (const float*)d_in[1];
    const int*   tw = (const int*)d_in[2];
    float* out = (float*)d_out;

    int8_t* Ai = (int8_t*)d_ws;                                   // 33,554,432 B
    int8_t* Bd = Ai + (size_t)B_DIM * CIN;                        // 12,582,912 B
    double* Sc = (double*)(Bd + (size_t)3 * COUT * CIN);          // 67,108,864 B
    unsigned long long* cm =
        (unsigned long long*)((int8_t*)Sc + (size_t)B_DIM * COUT * 8);  // 8,192 B

    hipLaunchKernelGGL(prep_x,  dim3(8192), dim3(256), 0, stream, x, Ai);
    hipLaunchKernelGGL(prep_w,  dim3(4096), dim3(256), 0, stream, W, Bd, cm);
    hipLaunchKernelGGL(gemm_i8, dim3(1024), dim3(256), 0, stream, Ai, Bd, Sc, cm);
    hipLaunchKernelGGL(scan_k,  dim3(2048), dim3(256), 0, stream, Sc, cm, tw, out);
}